// Round 7
// baseline (1107.731 us; speedup 1.0000x reference)
//
#include <hip/hip_runtime.h>

typedef unsigned short u16;
typedef unsigned int u32;
typedef __attribute__((ext_vector_type(8))) short short8;
typedef __attribute__((ext_vector_type(4))) float floatx4;
typedef __attribute__((ext_vector_type(4))) unsigned int u32x4;

#define SCALE_Q 0.17677669529663687f  // 32^-0.5

__device__ __forceinline__ u16 f2bf(float f) {
  u32 u = __float_as_uint(f);
  u = (u + 0x7fffu + ((u >> 16) & 1u)) >> 16;
  return (u16)u;
}

// HW packed fp32->bf16 (RNE), 1 instr per 2 floats (T12 recipe; no builtin on gfx950)
__device__ __forceinline__ u32 cvtpk(float lo, float hi) {
  u32 r;
  asm("v_cvt_pk_bf16_f32 %0, %1, %2" : "=v"(r) : "v"(lo), "v"(hi));
  return r;
}

__device__ __forceinline__ void gload_lds16(const void* g, void* l) {
  __builtin_amdgcn_global_load_lds(
      (const __attribute__((address_space(1))) u32*)g,
      (__attribute__((address_space(3))) u32*)l, 16, 0, 0);
}

__device__ __forceinline__ floatx4 mfma16(short8 a, short8 b, floatx4 c) {
  return __builtin_amdgcn_mfma_f32_16x16x32_bf16(a, b, c, 0, 0, 0);
}

// ---------------- prep: cast weights to bf16 ----------------
__global__ void cast_w_kernel(const float* __restrict__ qkv_w,
                              const float* __restrict__ proj_w,
                              u16* __restrict__ wb1, u16* __restrict__ wb2) {
  int idx = blockIdx.x * 256 + threadIdx.x;   // grid covers 442368 exactly
  wb1[idx] = f2bf(qkv_w[idx]);
  if (idx < 147456) wb2[idx] = f2bf(proj_w[idx]);
}

// ---- prep: combined bias+mask table: comb[w][h][query(64)][key(64)] ----
__global__ void comb_kernel(const float* __restrict__ bias_table,
                            const float* __restrict__ mask,
                            float* __restrict__ comb) {
  int wh = blockIdx.x;          // 768 = 64 windows * 12 heads
  int w = wh / 12, h = wh - w * 12;
  float* dst = comb + (size_t)wh * 4096;
  for (int e = threadIdx.x; e < 4096; e += 256) {
    int p = e >> 6, q = e & 63;   // p = query token, q = key token
    float v;
    if (q >= 49) v = -1e30f;          // padded key columns -> softmax zero
    else if (p >= 49) v = 0.0f;       // padded query rows: keep finite
    else {
      int pi = p / 7, pj = p - pi * 7;
      int qi = q / 7, qj = q - qi * 7;
      int ridx = (pi - qi + 6) * 13 + (pj - qj + 6);
      v = bias_table[ridx * 12 + h] + mask[(size_t)w * 2401 + p * 49 + q];
    }
    dst[e] = v;                       // e = query*64 + key
  }
}

// ---------------- QKV GEMM with FUSED x cast, BK=64: ----------------
// (200704x384 fp32) @ (1152x384 bf16)^T + b -> bf16 head-major.
// 6 iterations of {stage(B gload_lds x4 + A reg->cvtpk->ds_write x8) -> barrier ->
// 2 k-steps x 16 MFMA} — half the barrier/drain count of BK=32, 32 MFMAs per drain.
// LDS layout [m][slot(8)][8] with slot = kchunk ^ (m&7): coalesced staging, conflict-
// free b128 reads. Next-iter A loads issued right after the barrier (hidden under MFMA).
__global__ __launch_bounds__(256) void qkv_gemm(const float* __restrict__ X,
                                                const u16* __restrict__ B,
                                                const float* __restrict__ bias,
                                                u16* __restrict__ C) {
  __shared__ u16 As[8192];  // 16KB: [m(128)][slot(8)][8]
  __shared__ u16 Bs[8192];
  const int tid = threadIdx.x;
  const int lane = tid & 63;
  const int wave = tid >> 6;
  const int l15 = lane & 15;
  const int quad = lane >> 4;
  const int wr = wave >> 1, wc = wave & 1;
  // swizzle: grid 14112 = 8 xcd * 196 grp * 9 tn
  const u32 bid = blockIdx.x;
  const u32 xcd = bid & 7;
  const u32 slot = bid >> 3;        // 0..1763
  const u32 grp = slot / 9;
  const u32 tn = slot - grp * 9;
  const u32 tm = xcd * 196 + grp;   // 0..1567

  // A staging: row mA = tid>>4 (+16j), float4 chunk c4 = tid&15 (16 lanes = full 256B row)
  const int mA = tid >> 4, c4 = tid & 15;
  const float* Axp = X + (size_t)(tm * 128 + mA) * 384 + c4 * 4;
  // LDS: logical bf16 chunk kc = c4>>1, half = c4&1; slot = kc ^ (mA&7)  (16j keeps &7)
  const int sA0 = mA * 64 + (((c4 >> 1) ^ (mA & 7)) * 8) + (c4 & 1) * 4;  // +1024*j

  // B staging: 4 groups; slot s=c&7 holds global chunk kp = s ^ (m&7)
  const u16* Bbp[4];
  int ldB[4];
#pragma unroll
  for (int g = 0; g < 4; ++g) {
    const int c = tid + 256 * g;
    const int m = c >> 3, s = c & 7;
    const int kp = s ^ (m & 7);
    Bbp[g] = B + (size_t)(tn * 128 + m) * 384 + kp * 8;
    ldB[g] = c * 8;
  }

  floatx4 acc[4][4];
#pragma unroll
  for (int i = 0; i < 4; ++i)
#pragma unroll
    for (int j = 0; j < 4; ++j) acc[i][j] = (floatx4){0.f, 0.f, 0.f, 0.f};

  // prefetch A regs for kb=0 (8 x float4: rows mA+16j, 16 floats .. wait 4 floats each)
  float4 ar[8];
#pragma unroll
  for (int j = 0; j < 8; ++j) ar[j] = *(const float4*)(Axp + j * 6144);

  // read-side: frag row = w*64+i*16+l15 -> row&7 == l15&7
  const int l7 = l15 & 7;
  const int arow = (wr * 64 + l15) * 64;
  const int brow = (wc * 64 + l15) * 64;
  const int sl0 = (quad ^ l7) * 8;        // ks=0: kc=quad
  const int sl1 = ((4 + quad) ^ l7) * 8;  // ks=1: kc=4+quad

  for (int kb = 0; kb < 6; ++kb) {
    if (kb) __syncthreads();          // prior compute done; LDS reusable
    const int k0 = kb * 64;
#pragma unroll
    for (int g = 0; g < 4; ++g) gload_lds16(Bbp[g] + k0, &Bs[ldB[g]]);
#pragma unroll
    for (int j = 0; j < 8; ++j) {
      uint2 w2;
      w2.x = cvtpk(ar[j].x, ar[j].y);
      w2.y = cvtpk(ar[j].z, ar[j].w);
      *(uint2*)(&As[sA0 + 1024 * j]) = w2;
    }
    __syncthreads();                  // drains B gload + A ds_writes
    // issue next-iter A loads now: hidden under the 32 MFMAs below
    if (kb < 5) {
#pragma unroll
      for (int j = 0; j < 8; ++j)
        ar[j] = *(const float4*)(Axp + j * 6144 + (kb + 1) * 64);
    }
#pragma unroll
    for (int ks = 0; ks < 2; ++ks) {
      const int sl = ks ? sl1 : sl0;
      short8 af[4], bfr[4];
#pragma unroll
      for (int i = 0; i < 4; ++i)
        af[i] = *(const short8*)(&As[arow + i * 1024 + sl]);
#pragma unroll
      for (int i = 0; i < 4; ++i)
        bfr[i] = *(const short8*)(&Bs[brow + i * 1024 + sl]);
#pragma unroll
      for (int mi = 0; mi < 4; ++mi)
#pragma unroll
        for (int ni = 0; ni < 4; ++ni)
          acc[mi][ni] = mfma16(af[mi], bfr[ni], acc[mi][ni]);
    }
  }

  // epilogue: scale folded into fma, cvtpk pair conversion; head-major output
#pragma unroll
  for (int ni = 0; ni < 4; ++ni) {
    const int gbase = (int)tn * 128 + wc * 64 + ni * 16;   // 16-aligned, no head crossing
    const int which = gbase / 384;
    const int rem = gbase - which * 384;
    const int h = rem >> 5;
    const int db = rem & 31;
    const float scale = (which == 0) ? SCALE_Q : 1.0f;
    const float bbs = bias[gbase + l15] * scale;
    u16* hp = C + ((size_t)which * 49152 + h) * 1568 + db + l15;
#pragma unroll
    for (int mi = 0; mi < 4; ++mi) {
      const int grow0 = (int)tm * 128 + wr * 64 + mi * 16 + quad * 4;
#pragma unroll
      for (int rp = 0; rp < 2; ++rp) {
        const float v0 = acc[mi][ni][2 * rp] * scale + bbs;
        const float v1 = acc[mi][ni][2 * rp + 1] * scale + bbs;
        const u32 pkv = cvtpk(v0, v1);
        const int g0 = grow0 + 2 * rp, g1 = g0 + 1;
        const int b0 = g0 / 49, t0 = g0 - b0 * 49;
        const int b1 = g1 / 49, t1 = g1 - b1 * 49;
        hp[(size_t)b0 * 18816 + t0 * 32] = (u16)(pkv & 0xffffu);
        hp[(size_t)b1 * 18816 + t1 * 32] = (u16)(pkv >> 16);
      }
    }
  }
}

// ---------------- fused attention+proj: one block (4 waves) per window ----------------
// Swapped QK^T (St = mfma(K,Q)), lane-local softmax, shfl P^T transpose (no Ps LDS),
// next-head register prefetch (T14). All bf16 packing via HW v_cvt_pk_bf16_f32.
// LDS: aoS 50176 + 4x Vt 4608 = 68608 B -> 2 blocks/CU.
__global__ __launch_bounds__(256, 2) void attn_proj(const u16* __restrict__ qkv,
                                                    const float* __restrict__ comb,
                                                    const u16* __restrict__ pw,
                                                    const float* __restrict__ pb,
                                                    float* __restrict__ out) {
  __shared__ uint4 smem[4288];                              // 68608 B
  u16* aoS = (u16*)smem;                                    // [64][392]
  const int tid = threadIdx.x;
  const int lane = tid & 63;
  const int wv = tid >> 6;
  const int l15 = lane & 15, quad = lane >> 4;
  u16* Vt = (u16*)((char*)smem + 50176 + wv * 4608);        // [32][72] per wave

  const int bid = blockIdx.x;
  const int w = bid >> 6;                                   // comb slice shared in L2
  const int b = (bid & 63) * 64 + w;                        // b & 63 == w

  const floatx4 z4 = (floatx4){0.f, 0.f, 0.f, 0.f};
  const short8 z8 = {0, 0, 0, 0, 0, 0, 0, 0};

  // V slot geometry (lane-constant): slots svi=0..2 -> tokens (lane>>2)+svi*16,
  // slot 3 -> token 48 clamped (lanes >=4 are pad tokens 49..63, value zeroed on write).
  const int vcol = (lane & 3) * 8;
  const int vrow = lane >> 2;
  const int voff0 = vrow * 32 + vcol;

  // double register sets for head pipeline
  short8 aqR[2][4], bkR[2][4];
  uint4 vvR[2][4];

#define LOADH(HH, RR)                                                          \
  do {                                                                         \
    const int h_ = wv + (HH) * 4;                                              \
    const size_t ho_ = (size_t)(b * 12 + h_) * 1568;                           \
    const u16* qb_ = qkv + ho_;                                                \
    const u16* kb_ = qkv + (size_t)49152 * 1568 + ho_;                         \
    const u16* vb_ = qkv + (size_t)98304 * 1568 + ho_;                         \
    _Pragma("unroll") for (int i_ = 0; i_ < 3; ++i_) {                         \
      aqR[RR][i_] = *(const short8*)(qb_ + (i_ * 16 + l15) * 32 + quad * 8);   \
      bkR[RR][i_] = *(const short8*)(kb_ + (i_ * 16 + l15) * 32 + quad * 8);   \
    }                                                                          \
    aqR[RR][3] = (l15 == 0) ? *(const short8*)(qb_ + 48 * 32 + quad * 8) : z8; \
    bkR[RR][3] = (l15 == 0) ? *(const short8*)(kb_ + 48 * 32 + quad * 8) : z8; \
    vvR[RR][0] = *(const uint4*)(vb_ + voff0);                                 \
    vvR[RR][1] = *(const uint4*)(vb_ + voff0 + 16 * 32);                       \
    vvR[RR][2] = *(const uint4*)(vb_ + voff0 + 32 * 32);                       \
    vvR[RR][3] = *(const uint4*)(vb_ + 48 * 32 + vcol);                        \
  } while (0)

  LOADH(0, 0);

#pragma unroll
  for (int hi = 0; hi < 3; ++hi) {
    const int cu = hi & 1;
    const int h = wv + hi * 4;
    if (hi < 2) {
      if (hi == 0) LOADH(1, 1);
      else LOADH(2, 0);
    }

    // Vt write from current V regs (pad tokens zeroed)
#pragma unroll
    for (int svi = 0; svi < 4; ++svi) {
      uint4 dv = vvR[cu][svi];
      const int t = vrow + svi * 16;             // svi=3: 48..63
      if (svi == 3 && lane >= 4) dv = make_uint4(0u, 0u, 0u, 0u);
      const int d0 = (lane & 3) * 8;
      const u32 vvx[4] = {dv.x, dv.y, dv.z, dv.w};
#pragma unroll
      for (int e = 0; e < 4; ++e) {
        Vt[(d0 + 2 * e) * 72 + t] = (u16)(vvx[e] & 0xffffu);
        Vt[(d0 + 2 * e + 1) * 72 + t] = (u16)(vvx[e] >> 16);
      }
    }

    // St = K Q^T (swapped): row=key=mi*16+quad*4+r, col=query=ni*16+l15
    floatx4 st[4][4];
    __builtin_amdgcn_s_setprio(1);
#pragma unroll
    for (int mi = 0; mi < 4; ++mi)
#pragma unroll
      for (int ni = 0; ni < 4; ++ni) st[mi][ni] = mfma16(bkR[cu][mi], aqR[cu][ni], z4);
    __builtin_amdgcn_s_setprio(0);

    // comb[w][h][query][key]: float4 over key/reg axis
    const float* cb = comb + (size_t)(w * 12 + h) * 4096;
#pragma unroll
    for (int ni = 0; ni < 4; ++ni)
#pragma unroll
      for (int mi = 0; mi < 4; ++mi) {
        const float4 cv = *(const float4*)(cb + (ni * 16 + l15) * 64 + mi * 16 + quad * 4);
        st[mi][ni][0] += cv.x;
        st[mi][ni][1] += cv.y;
        st[mi][ni][2] += cv.z;
        st[mi][ni][3] += cv.w;
      }

    // softmax over keys: 16 lane-local + cross-quad shfl
    float rinv[4];
#pragma unroll
    for (int ni = 0; ni < 4; ++ni) {
      float mx = st[0][ni][0];
#pragma unroll
      for (int mi = 0; mi < 4; ++mi)
#pragma unroll
        for (int r = 0; r < 4; ++r) mx = fmaxf(mx, st[mi][ni][r]);
      mx = fmaxf(mx, __shfl_xor(mx, 16));
      mx = fmaxf(mx, __shfl_xor(mx, 32));
      float sum = 0.f;
#pragma unroll
      for (int mi = 0; mi < 4; ++mi)
#pragma unroll
        for (int r = 0; r < 4; ++r) {
          const float e = __expf(st[mi][ni][r] - mx);
          st[mi][ni][r] = e;
          sum += e;
        }
      sum += __shfl_xor(sum, 16);
      sum += __shfl_xor(sum, 32);
      rinv[ni] = 1.0f / sum;
    }

    // pack P^T to bf16 pairs (HW cvtpk): keys (mi*16+quad*4+2t, +1), query (ni,l15)
    u32 pk[4][4][2];
#pragma unroll
    for (int mi = 0; mi < 4; ++mi)
#pragma unroll
      for (int ni = 0; ni < 4; ++ni)
#pragma unroll
        for (int t = 0; t < 2; ++t)
          pk[mi][ni][t] = cvtpk(st[mi][ni][2 * t] * rinv[ni],
                                st[mi][ni][2 * t + 1] * rinv[ni]);

    // O^T = V^T P^T : M=32 dims (mb), N=64 queries (nb), K=64 keys (kk)
    floatx4 ot[2][4];
#pragma unroll
    for (int mb = 0; mb < 2; ++mb)
#pragma unroll
      for (int nb = 0; nb < 4; ++nb) ot[mb][nb] = z4;

    const int srcLo = ((quad & 1) * 2) * 16 + l15;
    const int srcHi = srcLo + 16;
    const bool hiSel = (quad >> 1) != 0;
#pragma unroll
    for (int kk = 0; kk < 2; ++kk) {
      short8 av[2];
#pragma unroll
      for (int mb = 0; mb < 2; ++mb)
        av[mb] = *(const short8*)(Vt + (mb * 16 + l15) * 72 + kk * 32 + quad * 8);
#pragma unroll
      for (int nb = 0; nb < 4; ++nb) {
        const int ma = kk * 2, mbx = kk * 2 + 1;
        const u32 a0 = __shfl(pk[ma][nb][0], srcLo), b0 = __shfl(pk[mbx][nb][0], srcLo);
        const u32 a1 = __shfl(pk[ma][nb][1], srcLo), b1 = __shfl(pk[mbx][nb][1], srcLo);
        const u32 a2 = __shfl(pk[ma][nb][0], srcHi), b2 = __shfl(pk[mbx][nb][0], srcHi);
        const u32 a3 = __shfl(pk[ma][nb][1], srcHi), b3 = __shfl(pk[mbx][nb][1], srcHi);
        u32x4 tv = {hiSel ? b0 : a0, hiSel ? b1 : a1, hiSel ? b2 : a2, hiSel ? b3 : a3};
        const short8 pbv = __builtin_bit_cast(short8, tv);
        __builtin_amdgcn_s_setprio(1);
#pragma unroll
        for (int mb = 0; mb < 2; ++mb) ot[mb][nb] = mfma16(av[mb], pbv, ot[mb][nb]);
        __builtin_amdgcn_s_setprio(0);
      }
    }

    // O^T: row=dim=mb*16+quad*4+r, col=query=nb*16+l15 -> aoS[query][h*32+dim]
#pragma unroll
    for (int mb = 0; mb < 2; ++mb)
#pragma unroll
      for (int nb = 0; nb < 4; ++nb) {
        uint2 uv;
        uv.x = cvtpk(ot[mb][nb][0], ot[mb][nb][1]);
        uv.y = cvtpk(ot[mb][nb][2], ot[mb][nb][3]);
        *(uint2*)(aoS + (nb * 16 + l15) * 392 + h * 32 + mb * 16 + quad * 4) = uv;
      }
  }
#undef LOADH

  __syncthreads();  // aoS complete across all waves

  // ---- proj GEMM: (64x384 from aoS) @ (384x384 pw)^T, wave wv owns cols wv*96..+96 ----
  floatx4 pacc[4][6];
#pragma unroll
  for (int mi = 0; mi < 4; ++mi)
#pragma unroll
    for (int nf = 0; nf < 6; ++nf) pacc[mi][nf] = z4;

  const u16* pwb = pw + (size_t)(wv * 96 + l15) * 384 + quad * 8;
#pragma unroll
  for (int kb = 0; kb < 12; ++kb) {
    short8 paf[4], pbf[6];
#pragma unroll
    for (int mi = 0; mi < 4; ++mi)
      paf[mi] = *(const short8*)(aoS + (mi * 16 + l15) * 392 + kb * 32 + quad * 8);
#pragma unroll
    for (int nf = 0; nf < 6; ++nf)
      pbf[nf] = *(const short8*)(pwb + nf * 6144 + kb * 32);
    __builtin_amdgcn_s_setprio(1);
#pragma unroll
    for (int mi = 0; mi < 4; ++mi)
#pragma unroll
      for (int nf = 0; nf < 6; ++nf)
        pacc[mi][nf] = mfma16(paf[mi], pbf[nf], pacc[mi][nf]);
    __builtin_amdgcn_s_setprio(0);
  }

#pragma unroll
  for (int nf = 0; nf < 6; ++nf) {
    const int col = wv * 96 + nf * 16 + l15;
    const float bb = pb[col];
#pragma unroll
    for (int mi = 0; mi < 4; ++mi)
#pragma unroll
      for (int r = 0; r < 4; ++r) {
        const int row = mi * 16 + quad * 4 + r;
        if (row < 49)
          out[((size_t)b * 49 + row) * 384 + col] = pacc[mi][nf][r] + bb;
      }
  }
}

// ---------------- launcher ----------------
extern "C" void kernel_launch(void* const* d_in, const int* in_sizes, int n_in,
                              void* d_out, int out_size, void* d_ws, size_t ws_size,
                              hipStream_t stream) {
  const float* x = (const float*)d_in[0];
  const float* mask = (const float*)d_in[1];
  const float* qkv_w = (const float*)d_in[2];
  const float* qkv_b = (const float*)d_in[3];
  const float* proj_w = (const float*)d_in[4];
  const float* proj_b = (const float*)d_in[5];
  const float* bias_table = (const float*)d_in[6];
  float* out = (float*)d_out;
  char* ws = (char*)d_ws;

  u16* wb1 = (u16*)(ws);                        // 442368 bf16 = 884736 B
  u16* wb2 = (u16*)(ws + 884736);               // 147456 bf16 = 294912 B
  float* comb = (float*)(ws + 1179648);         // 768*4096 f32 = 12582912 B
  u16* qkvb = (u16*)(ws + 13762560);            // 200704*1152 bf16 = 462422016 B (head-major)
  // x is cast in-kernel; total ws use: 476184576 B

  hipLaunchKernelGGL(cast_w_kernel, dim3(1728), dim3(256), 0, stream, qkv_w, proj_w, wb1, wb2);
  hipLaunchKernelGGL(comb_kernel, dim3(768), dim3(256), 0, stream, bias_table, mask, comb);
  hipLaunchKernelGGL(qkv_gemm, dim3(14112), dim3(256), 0, stream, x, wb1, qkv_b, qkvb);
  hipLaunchKernelGGL(attn_proj, dim3(4096), dim3(256), 0, stream, qkvb, comb, wb2, proj_b, out);
}